// Round 2
// baseline (1579.647 us; speedup 1.0000x reference)
//
#include <hip/hip_runtime.h>
#include <hip/hip_cooperative_groups.h>

namespace cg = cooperative_groups;

#define IN_F 1024
#define ASS 100000
#define OUT_F 1024
#define TOTAL (IN_F + ASS + OUT_F)
#define ASS0 IN_F
#define OUT0 (IN_F + ASS)
#define NUM_ROUNDS 24

#define NBLK 512
#define NTHR 256
#define CHUNK 196  // ceil(ASS / NBLK), must be <= NTHR

// ---------------------------------------------------------------------------
// Cooperative single-kernel implementation.
// Workspace layout (ints/floats are 4B):
//   mem[TOTAL] delta[TOTAL] status[TOTAL] got[TOTAL]
//   row_start[ASS+1] cursor[ASS] f0[ASS] f1[ASS] cnt[64] bsum[NBLK]
//   csr_dst[E_a] csr_w[E_a]
// ---------------------------------------------------------------------------

__global__ __launch_bounds__(NTHR) void coop_kernel(
    const float* __restrict__ x, const float* __restrict__ iw,
    const float* __restrict__ aw, const int* __restrict__ ies,
    const int* __restrict__ ied, const int* __restrict__ aes,
    const int* __restrict__ aed, int E_in, int E_a, char* ws,
    float* __restrict__ out) {
  cg::grid_group grid = cg::this_grid();

  float* mem = (float*)ws;
  float* delta = mem + TOTAL;
  int* status = (int*)(delta + TOTAL);
  int* got = status + TOTAL;
  int* row_start = got + TOTAL;       // ASS+1
  int* cursor = row_start + ASS + 1;  // ASS (doubles as count)
  int* f0 = cursor + ASS;             // ASS
  int* f1 = f0 + ASS;                 // ASS
  int* cnt = f1 + ASS;                // 64 (cnt[0] at 0, cnt[1] at 32)
  int* bsum = cnt + 64;               // NBLK
  int* csr_dst = bsum + NBLK;         // E_a
  float* csr_w = (float*)(csr_dst + E_a);

  const int gtid = blockIdx.x * NTHR + threadIdx.x;
  const int gsize = NBLK * NTHR;
  const int tid = threadIdx.x;

  __shared__ int lds[NTHR];
  __shared__ int s_nf;

  // ---- phase 0: zero state ----
  for (int i = gtid; i < TOTAL; i += gsize) {
    mem[i] = 0.f;
    delta[i] = 0.f;
    status[i] = 0;
    got[i] = 0;
  }
  for (int i = gtid; i < ASS; i += gsize) cursor[i] = 0;
  if (gtid < 64) cnt[gtid] = 0;
  grid.sync();

  // ---- phase 1: histogram of assoc-edge sources ----
  for (int e = gtid; e < E_a; e += gsize)
    atomicAdd(&cursor[aes[e] - ASS0], 1);
  grid.sync();

  // ---- phase 2a: per-block partial sums of counts ----
  {
    int c0 = blockIdx.x * CHUNK;
    int c1 = min(c0 + CHUNK, ASS);
    int s = 0;
    for (int c = c0 + tid; c < c1; c += NTHR) s += cursor[c];
    lds[tid] = s;
    __syncthreads();
    for (int off = NTHR / 2; off > 0; off >>= 1) {
      if (tid < off) lds[tid] += lds[tid + off];
      __syncthreads();
    }
    if (tid == 0) bsum[blockIdx.x] = lds[0];
  }
  grid.sync();

  // ---- phase 2b: block 0 exclusive-scans the NBLK block sums ----
  if (blockIdx.x == 0) {
    int b0 = bsum[2 * tid];
    int b1 = bsum[2 * tid + 1];
    lds[tid] = b0 + b1;
    __syncthreads();
    for (int off = 1; off < NTHR; off <<= 1) {
      int v = (tid >= off) ? lds[tid - off] : 0;
      __syncthreads();
      lds[tid] += v;
      __syncthreads();
    }
    int excl_pair = (tid > 0) ? lds[tid - 1] : 0;
    bsum[2 * tid] = excl_pair;
    bsum[2 * tid + 1] = excl_pair + b0;
  }
  grid.sync();

  // ---- phase 2c: per-block exclusive scan of its chunk -> row_start/cursor --
  {
    int c0 = blockIdx.x * CHUNK;
    int c = c0 + tid;
    int v = (tid < CHUNK && c < ASS) ? cursor[c] : 0;
    lds[tid] = v;
    __syncthreads();
    for (int off = 1; off < NTHR; off <<= 1) {
      int t = (tid >= off) ? lds[tid - off] : 0;
      __syncthreads();
      lds[tid] += t;
      __syncthreads();
    }
    int excl = lds[tid] - v;
    int gofs = bsum[blockIdx.x];
    if (tid < CHUNK && c < ASS) {
      row_start[c] = gofs + excl;
      cursor[c] = gofs + excl;
    }
    if (gtid == 0) row_start[ASS] = E_a;
  }
  grid.sync();

  // ---- phase 3: scatter edges into CSR ----
  for (int e = gtid; e < E_a; e += gsize) {
    int s = aes[e] - ASS0;
    int pos = atomicAdd(&cursor[s], 1);
    csr_dst[pos] = aed[e];
    csr_w[pos] = aw[e];
  }
  grid.sync();

  // ---- phase 4: input phase ----
  for (int e = gtid; e < E_in; e += gsize) {
    atomicAdd(&mem[ied[e]], x[ies[e]] * iw[e]);
    got[ied[e]] = 1;
  }
  grid.sync();

  // ---- phase 5: initial status + frontier 0 ----
  for (int i = gtid; i < TOTAL; i += gsize) {
    if (got[i]) {
      status[i] = 1;
      got[i] = 0;
      if (i >= ASS0 && i < OUT0) {
        int pos = atomicAdd(&cnt[0], 1);
        f0[pos] = i;
      }
    }
  }
  grid.sync();

  // ---- phase 6: propagation rounds ----
  const int wid = gtid >> 6;
  const int lane = tid & 63;
  const int nwaves = gsize >> 6;
  for (int r = 0; r < NUM_ROUNDS; ++r) {
    int p = r & 1;
    if (tid == 0)
      s_nf = __hip_atomic_load(&cnt[p * 32], __ATOMIC_RELAXED,
                               __HIP_MEMORY_SCOPE_AGENT);
    __syncthreads();
    int nf = s_nf;
    if (nf == 0) break;  // all later rounds are no-ops
    const int* fr = p ? f1 : f0;
    int* fn = p ? f0 : f1;

    // edge pass: one wave per frontier node
    for (int f = wid; f < nf; f += nwaves) {
      int u = fr[f];
      int ui = u - ASS0;
      int base = row_start[ui];
      int end = row_start[ui + 1];
      float tv = tanhf(mem[u]);
      for (int e = base + lane; e < end; e += 64) {
        int d = csr_dst[e];
        atomicAdd(&delta[d], tv * csr_w[e]);
        got[d] = 1;
      }
    }
    grid.sync();

    // node update (dense over TOTAL)
    if (gtid == 0)
      __hip_atomic_store(&cnt[p * 32], 0, __ATOMIC_RELAXED,
                         __HIP_MEMORY_SCOPE_AGENT);
    for (int i = gtid; i < TOTAL; i += gsize) {
      int st = status[i];
      float d = delta[i];
      int g = got[i];
      bool assoc = (i >= ASS0) && (i < OUT0);
      bool fire = (st == 1) && assoc;
      mem[i] = fire ? d : mem[i] + d;
      int ns = fire ? 2 : ((g && st == 0) ? 1 : st);
      if (ns != st) status[i] = ns;
      if (ns == 1 && st == 0 && assoc) {
        int pos = atomicAdd(&cnt[(p ^ 1) * 32], 1);
        fn[pos] = i;
      }
      if (d != 0.f) delta[i] = 0.f;
      if (g) got[i] = 0;
    }
    grid.sync();
  }

  // ---- phase 7: output ----
  for (int i = gtid; i < OUT_F; i += gsize) out[i] = tanhf(mem[OUT0 + i]);
}

// ---------------------------------------------------------------------------
// Fallback dense multi-kernel path (round-1 implementation) if ws too small.
// ---------------------------------------------------------------------------

__global__ __launch_bounds__(256) void k_init(float* mem, float* delta,
                                              int* status, int* got) {
  int i = blockIdx.x * 256 + threadIdx.x;
  if (i < TOTAL) {
    mem[i] = 0.f;
    delta[i] = 0.f;
    status[i] = 0;
    got[i] = 0;
  }
}

__global__ __launch_bounds__(256) void k_input(const float* __restrict__ x,
                                               const float* __restrict__ w,
                                               const int* __restrict__ src,
                                               const int* __restrict__ dst,
                                               int n, float* mem, int* got) {
  for (int e = blockIdx.x * 256 + threadIdx.x; e < n; e += gridDim.x * 256) {
    atomicAdd(&mem[dst[e]], x[src[e]] * w[e]);
    got[dst[e]] = 1;
  }
}

__global__ __launch_bounds__(256) void k_status0(int* status, int* got) {
  int i = blockIdx.x * 256 + threadIdx.x;
  if (i < TOTAL) {
    status[i] = got[i] ? 1 : 0;
    got[i] = 0;
  }
}

__global__ __launch_bounds__(256) void k_edge(const float* __restrict__ w,
                                              const int* __restrict__ src,
                                              const int* __restrict__ dst,
                                              int n,
                                              const float* __restrict__ mem,
                                              const int* __restrict__ status,
                                              float* delta, int* got) {
  for (int e = blockIdx.x * 256 + threadIdx.x; e < n; e += gridDim.x * 256) {
    int s = src[e];
    if (status[s] == 1) {
      float v = tanhf(mem[s]) * w[e];
      int d = dst[e];
      atomicAdd(&delta[d], v);
      got[d] = 1;
    }
  }
}

__global__ __launch_bounds__(256) void k_update(float* mem, float* delta,
                                                int* status, int* got) {
  int i = blockIdx.x * 256 + threadIdx.x;
  if (i < TOTAL) {
    int st = status[i];
    bool fire = (st == 1) && (i >= ASS0) && (i < OUT0);
    float d = delta[i];
    mem[i] = fire ? d : (mem[i] + d);
    status[i] = fire ? 2 : ((got[i] && st == 0) ? 1 : st);
    delta[i] = 0.f;
    got[i] = 0;
  }
}

__global__ __launch_bounds__(256) void k_out(const float* __restrict__ mem,
                                             float* __restrict__ out) {
  int i = blockIdx.x * 256 + threadIdx.x;
  if (i < OUT_F) out[i] = tanhf(mem[OUT0 + i]);
}

extern "C" void kernel_launch(void* const* d_in, const int* in_sizes, int n_in,
                              void* d_out, int out_size, void* d_ws,
                              size_t ws_size, hipStream_t stream) {
  const float* x = (const float*)d_in[0];
  const float* iw = (const float*)d_in[1];
  const float* aw = (const float*)d_in[2];
  const int* ies = (const int*)d_in[3];
  const int* ied = (const int*)d_in[4];
  const int* aes = (const int*)d_in[5];
  const int* aed = (const int*)d_in[6];
  int E_in = in_sizes[1];
  int E_a = in_sizes[2];
  float* out = (float*)d_out;
  char* ws = (char*)d_ws;

  size_t need = ((size_t)4 * TOTAL + (ASS + 1) + 3 * (size_t)ASS + 64 + NBLK) *
                    4 +
                (size_t)E_a * 8;

  if (ws_size >= need) {
    void* args[] = {&x,   &ies, &ied, &aes, &aed, &iw,
                    &aw,  &E_in, &E_a, &ws,  &out};
    // NOTE: argument order must match kernel signature:
    // (x, iw, aw, ies, ied, aes, aed, E_in, E_a, ws, out)
    void* args2[] = {(void*)&x,    (void*)&iw,  (void*)&aw,  (void*)&ies,
                     (void*)&ied,  (void*)&aes, (void*)&aed, (void*)&E_in,
                     (void*)&E_a,  (void*)&ws,  (void*)&out};
    (void)args;
    hipLaunchCooperativeKernel((void*)coop_kernel, dim3(NBLK), dim3(NTHR),
                               args2, 0, stream);
    return;
  }

  // fallback: dense path
  float* mem = (float*)ws;
  float* delta = mem + TOTAL;
  int* status = (int*)(delta + TOTAL);
  int* got = status + TOTAL;
  const int nodeBlocks = (TOTAL + 255) / 256;
  k_init<<<nodeBlocks, 256, 0, stream>>>(mem, delta, status, got);
  int inBlocks = (E_in + 255) / 256;
  if (inBlocks > 1024) inBlocks = 1024;
  k_input<<<inBlocks, 256, 0, stream>>>(x, iw, ies, ied, E_in, mem, got);
  k_status0<<<nodeBlocks, 256, 0, stream>>>(status, got);
  int eBlocks = (E_a + 255) / 256;
  if (eBlocks > 2048) eBlocks = 2048;
  for (int r = 0; r < NUM_ROUNDS; ++r) {
    k_edge<<<eBlocks, 256, 0, stream>>>(aw, aes, aed, E_a, mem, status, delta,
                                        got);
    k_update<<<nodeBlocks, 256, 0, stream>>>(mem, delta, status, got);
  }
  k_out<<<(OUT_F + 255) / 256, 256, 0, stream>>>(mem, out);
}

// Round 3
// 1113.681 us; speedup vs baseline: 1.4184x; 1.4184x over previous
//
#include <hip/hip_runtime.h>
#include <hip/hip_cooperative_groups.h>

namespace cg = cooperative_groups;

#define IN_F 1024
#define ASS 100000
#define OUT_F 1024
#define TOTAL (IN_F + ASS + OUT_F)
#define ASS0 IN_F
#define OUT0 (IN_F + ASS)
#define NUM_ROUNDS 24

#define NBLK 1024
#define NTHR 256

// ---------------------------------------------------------------------------
// Fused BFS + value propagation, single cooperative kernel, no CSR.
//
// Facts used (provable from reference semantics):
//  * Each assoc neuron fires exactly once, at round L(u) where
//    L(u) = 0 for input receivers, else 1 + min_{v->u} L(v)  (BFS level).
//  * m*_u (memory at fire time) = input_contrib(u)
//        + sum_{v->u, L(v) < L(u)} tanh(m*_v) * w.
//  * Same-round deliveries land AFTER the fire (into the zeroed mem).
//  * Once a round has an empty frontier, all later rounds are no-ops.
//
// Per round r:
//   step1 (node scan, 100KB): if lev[u]==r: t[u]=tanh(mem[u]); mem[u]=0;
//          flag round as non-empty.
//   step2 (edge scan): if lev[src]==r: mem[dst]+=t[src]*w (atomic);
//          lev[dst]=r+1 if unset (benign race, all writers agree).
//
// Workspace: mem[TOTAL] f32, t[TOTAL] f32, lev[TOTAL] u8, flags[32] i32.
// ---------------------------------------------------------------------------

__global__ __launch_bounds__(NTHR) void coop2(
    const float* __restrict__ x, const float* __restrict__ iw,
    const float* __restrict__ aw, const int* __restrict__ ies,
    const int* __restrict__ ied, const int* __restrict__ aes,
    const int* __restrict__ aed, int E_in, int E_a, char* ws,
    float* __restrict__ out) {
  cg::grid_group grid = cg::this_grid();

  float* mem = (float*)ws;
  float* tv = mem + TOTAL;
  unsigned char* lev = (unsigned char*)(tv + TOTAL);
  int* flags = (int*)(lev + ((TOTAL + 3) & ~3));

  const int gtid = blockIdx.x * NTHR + threadIdx.x;
  const int gsize = NBLK * NTHR;

  __shared__ int s_any;

  // ---- init ----
  for (int i = gtid; i < TOTAL; i += gsize) {
    mem[i] = 0.f;
    lev[i] = 255;
  }
  if (gtid < 32) flags[gtid] = 0;
  grid.sync();

  // ---- input phase: seed mem, level 0 ----
  for (int e = gtid; e < E_in; e += gsize) {
    int d = ied[e];
    atomicAdd(&mem[d], x[ies[e]] * iw[e]);
    lev[d] = 0;  // benign race, all writers store 0
  }
  grid.sync();

  // ---- rounds ----
  const int4* aes4 = (const int4*)aes;
  const int nv4 = E_a >> 2;

  for (int r = 0; r < NUM_ROUNDS; ++r) {
    const unsigned char rl = (unsigned char)r;
    const unsigned char rn = (unsigned char)(r + 1);

    // step1: snapshot frontier activations, zero their memory
    bool any = false;
    for (int i = ASS0 + gtid; i < OUT0; i += gsize) {
      if (lev[i] == rl) {
        tv[i] = tanhf(mem[i]);
        mem[i] = 0.f;
        any = true;
      }
    }
    if (any) flags[r] = 1;  // benign race
    grid.sync();

    if (threadIdx.x == 0) s_any = flags[r];
    __syncthreads();
    if (!s_any) break;  // uniform across grid: all read same flags[r]

    // step2: edge scan — deliver from frontier sources
    for (int v = gtid; v < nv4; v += gsize) {
      int4 s4 = aes4[v];
      int e0 = v << 2;
#pragma unroll
      for (int j = 0; j < 4; ++j) {
        int s = (j == 0) ? s4.x : (j == 1) ? s4.y : (j == 2) ? s4.z : s4.w;
        if (lev[s] == rl) {
          int e = e0 + j;
          int d = aed[e];
          atomicAdd(&mem[d], tv[s] * aw[e]);
          if (lev[d] == 255) lev[d] = rn;
        }
      }
    }
    for (int e = (nv4 << 2) + gtid; e < E_a; e += gsize) {
      int s = aes[e];
      if (lev[s] == rl) {
        int d = aed[e];
        atomicAdd(&mem[d], tv[s] * aw[e]);
        if (lev[d] == 255) lev[d] = rn;
      }
    }
    grid.sync();
  }

  // ---- output ----
  for (int i = gtid; i < OUT_F; i += gsize) out[i] = tanhf(mem[OUT0 + i]);
}

// ---------------------------------------------------------------------------
// Fallback dense multi-kernel path (round-1 implementation) if ws too small.
// ---------------------------------------------------------------------------

__global__ __launch_bounds__(256) void k_init(float* mem, float* delta,
                                              int* status, int* got) {
  int i = blockIdx.x * 256 + threadIdx.x;
  if (i < TOTAL) {
    mem[i] = 0.f;
    delta[i] = 0.f;
    status[i] = 0;
    got[i] = 0;
  }
}

__global__ __launch_bounds__(256) void k_input(const float* __restrict__ x,
                                               const float* __restrict__ w,
                                               const int* __restrict__ src,
                                               const int* __restrict__ dst,
                                               int n, float* mem, int* got) {
  for (int e = blockIdx.x * 256 + threadIdx.x; e < n; e += gridDim.x * 256) {
    atomicAdd(&mem[dst[e]], x[src[e]] * w[e]);
    got[dst[e]] = 1;
  }
}

__global__ __launch_bounds__(256) void k_status0(int* status, int* got) {
  int i = blockIdx.x * 256 + threadIdx.x;
  if (i < TOTAL) {
    status[i] = got[i] ? 1 : 0;
    got[i] = 0;
  }
}

__global__ __launch_bounds__(256) void k_edge(const float* __restrict__ w,
                                              const int* __restrict__ src,
                                              const int* __restrict__ dst,
                                              int n,
                                              const float* __restrict__ mem,
                                              const int* __restrict__ status,
                                              float* delta, int* got) {
  for (int e = blockIdx.x * 256 + threadIdx.x; e < n; e += gridDim.x * 256) {
    int s = src[e];
    if (status[s] == 1) {
      float v = tanhf(mem[s]) * w[e];
      int d = dst[e];
      atomicAdd(&delta[d], v);
      got[d] = 1;
    }
  }
}

__global__ __launch_bounds__(256) void k_update(float* mem, float* delta,
                                                int* status, int* got) {
  int i = blockIdx.x * 256 + threadIdx.x;
  if (i < TOTAL) {
    int st = status[i];
    bool fire = (st == 1) && (i >= ASS0) && (i < OUT0);
    float d = delta[i];
    mem[i] = fire ? d : (mem[i] + d);
    status[i] = fire ? 2 : ((got[i] && st == 0) ? 1 : st);
    delta[i] = 0.f;
    got[i] = 0;
  }
}

__global__ __launch_bounds__(256) void k_out(const float* __restrict__ mem,
                                             float* __restrict__ out) {
  int i = blockIdx.x * 256 + threadIdx.x;
  if (i < OUT_F) out[i] = tanhf(mem[OUT0 + i]);
}

extern "C" void kernel_launch(void* const* d_in, const int* in_sizes, int n_in,
                              void* d_out, int out_size, void* d_ws,
                              size_t ws_size, hipStream_t stream) {
  const float* x = (const float*)d_in[0];
  const float* iw = (const float*)d_in[1];
  const float* aw = (const float*)d_in[2];
  const int* ies = (const int*)d_in[3];
  const int* ied = (const int*)d_in[4];
  const int* aes = (const int*)d_in[5];
  const int* aed = (const int*)d_in[6];
  int E_in = in_sizes[1];
  int E_a = in_sizes[2];
  float* out = (float*)d_out;
  char* ws = (char*)d_ws;

  size_t need = (size_t)TOTAL * 4 * 2 + ((TOTAL + 3) & ~3) + 32 * 4;

  if (ws_size >= need) {
    void* args[] = {(void*)&x,   (void*)&iw,  (void*)&aw,  (void*)&ies,
                    (void*)&ied, (void*)&aes, (void*)&aed, (void*)&E_in,
                    (void*)&E_a, (void*)&ws,  (void*)&out};
    hipLaunchCooperativeKernel((void*)coop2, dim3(NBLK), dim3(NTHR), args, 0,
                               stream);
    return;
  }

  // fallback: dense path
  float* mem = (float*)ws;
  float* delta = mem + TOTAL;
  int* status = (int*)(delta + TOTAL);
  int* got = status + TOTAL;
  const int nodeBlocks = (TOTAL + 255) / 256;
  k_init<<<nodeBlocks, 256, 0, stream>>>(mem, delta, status, got);
  int inBlocks = (E_in + 255) / 256;
  if (inBlocks > 1024) inBlocks = 1024;
  k_input<<<inBlocks, 256, 0, stream>>>(x, iw, ies, ied, E_in, mem, got);
  k_status0<<<nodeBlocks, 256, 0, stream>>>(status, got);
  int eBlocks = (E_a + 255) / 256;
  if (eBlocks > 2048) eBlocks = 2048;
  for (int r = 0; r < NUM_ROUNDS; ++r) {
    k_edge<<<eBlocks, 256, 0, stream>>>(aw, aes, aed, E_a, mem, status, delta,
                                        got);
    k_update<<<nodeBlocks, 256, 0, stream>>>(mem, delta, status, got);
  }
  k_out<<<(OUT_F + 255) / 256, 256, 0, stream>>>(mem, out);
}

// Round 4
// 251.433 us; speedup vs baseline: 6.2826x; 4.4293x over previous
//
#include <hip/hip_runtime.h>

#define IN_F 1024
#define ASS 100000
#define OUT_F 1024
#define TOTAL (IN_F + ASS + OUT_F)  // 102048
#define ASS0 IN_F
#define OUT0 (IN_F + ASS)
#define NDST (ASS + OUT_F)  // 101024 possible destinations, node id = ASS0+d
#define NUM_ROUNDS 24

#define BIN_SZ 128                            // dst nodes per bin (7 bits)
#define NBINS ((NDST + BIN_SZ - 1) / BIN_SZ)  // 790
#define NCON 512                              // construction blocks

// ---------------------------------------------------------------------------
// Structure: each assoc neuron fires exactly once at BFS level L(u).
// Per round r (one kernel, one block per 128-dst bin):
//   active edges (lev[src]==r) accumulate tanh(mem_cur[src])*w into an LDS
//   slice; then the block exclusively writes its slice of mem_next:
//   mem_next[d] = (fired ? 0 : mem_cur[d]) + slice[d].  No global atomics.
// Double-buffered mem (kernel r reads buf[r&1], writes buf[(r+1)&1]); empty
// rounds still copy so parity is static. Early-exit via flags[r].
// ---------------------------------------------------------------------------

__global__ __launch_bounds__(256) void kz(float* mem_a, unsigned int* lev32,
                                          int* flags, int* bin_count) {
  int i = blockIdx.x * 256 + threadIdx.x;
  int gs = gridDim.x * 256;
  for (int k = i; k < TOTAL; k += gs) mem_a[k] = 0.f;
  for (int k = i; k < TOTAL / 4; k += gs) lev32[k] = 0xFFFFFFFFu;
  for (int k = i; k < NBINS; k += gs) bin_count[k] = 0;
  if (i < 32) flags[i] = 0;
}

__global__ __launch_bounds__(256) void ki(const float* __restrict__ x,
                                          const float* __restrict__ iw,
                                          const int* __restrict__ ies,
                                          const int* __restrict__ ied, int E_in,
                                          float* mem_a, unsigned char* lev) {
  int e = blockIdx.x * 256 + threadIdx.x;
  if (e < E_in) {
    int d = ied[e];
    atomicAdd(&mem_a[d], x[ies[e]] * iw[e]);
    lev[d] = 0;  // benign race: all writers store 0
  }
}

// histogram of edges per dst-bin
__global__ __launch_bounds__(256) void kh(const int* __restrict__ aed, int E_a,
                                          int* bin_count) {
  __shared__ int h[NBINS];
  for (int b = threadIdx.x; b < NBINS; b += 256) h[b] = 0;
  __syncthreads();
  int chunk = (E_a + NCON - 1) / NCON;
  int lo = blockIdx.x * chunk;
  int hi = min(lo + chunk, E_a);
  for (int e = lo + (int)threadIdx.x; e < hi; e += 256)
    atomicAdd(&h[(aed[e] - ASS0) >> 7], 1);
  __syncthreads();
  for (int b = threadIdx.x; b < NBINS; b += 256)
    if (h[b]) atomicAdd(&bin_count[b], h[b]);
}

// exclusive scan of bin counts (single block)
__global__ __launch_bounds__(256) void ks(const int* __restrict__ bin_count,
                                          int* bin_start, int* bin_cursor) {
  __shared__ int sb[1024];
  __shared__ int sp[256];
  int tid = threadIdx.x;
  for (int k = 0; k < 4; ++k) {
    int t = tid + k * 256;
    sb[t] = (t < NBINS) ? bin_count[t] : 0;
  }
  __syncthreads();
  int i0 = tid * 4;
  int s = sb[i0] + sb[i0 + 1] + sb[i0 + 2] + sb[i0 + 3];
  sp[tid] = s;
  __syncthreads();
  for (int off = 1; off < 256; off <<= 1) {
    int v = (tid >= off) ? sp[tid - off] : 0;
    __syncthreads();
    sp[tid] += v;
    __syncthreads();
  }
  int run = (tid > 0) ? sp[tid - 1] : 0;
  for (int j = 0; j < 4; ++j) {
    int t = i0 + j;
    if (t < NBINS) {
      bin_start[t] = run;
      bin_cursor[t] = run;
    }
    run += sb[t];
  }
  if (tid == 255) bin_start[NBINS] = sp[255];
}

// scatter edges into bin-grouped layout; payload = (src<<7 | dstoff, w)
__global__ __launch_bounds__(256) void kc(const int* __restrict__ aes,
                                          const int* __restrict__ aed,
                                          const float* __restrict__ aw, int E_a,
                                          int* bin_cursor,
                                          uint2* __restrict__ csr) {
  __shared__ int h[NBINS];
  for (int b = threadIdx.x; b < NBINS; b += 256) h[b] = 0;
  __syncthreads();
  int chunk = (E_a + NCON - 1) / NCON;
  int lo = blockIdx.x * chunk;
  int hi = min(lo + chunk, E_a);
  for (int e = lo + (int)threadIdx.x; e < hi; e += 256)
    atomicAdd(&h[(aed[e] - ASS0) >> 7], 1);
  __syncthreads();
  for (int b = threadIdx.x; b < NBINS; b += 256) {
    int c = h[b];
    if (c) h[b] = atomicAdd(&bin_cursor[b], c);  // count -> global base
  }
  __syncthreads();
  for (int e = lo + (int)threadIdx.x; e < hi; e += 256) {
    int d = aed[e] - ASS0;
    int b = d >> 7;
    int pos = atomicAdd(&h[b], 1);  // LDS cursor
    csr[pos] = make_uint2(((unsigned)aes[e] << 7) | (unsigned)(d & 127),
                          __float_as_uint(aw[e]));
  }
}

// one propagation round; grid = NBINS blocks, block owns dst [bin*128, ...)
__global__ __launch_bounds__(256) void kR(int r, int* flags,
                                          const int* __restrict__ bin_start,
                                          const uint2* __restrict__ csr,
                                          const float* __restrict__ mcur,
                                          float* __restrict__ mnext,
                                          unsigned char* lev) {
  __shared__ float slice[BIN_SZ];
  __shared__ int smask[BIN_SZ];
  __shared__ int newfront;
  int tid = threadIdx.x;
  int bin = blockIdx.x;
  bool active = (r == 0) || (flags[r] != 0);
  if (tid < BIN_SZ) {
    slice[tid] = 0.f;
    smask[tid] = 0;
  }
  if (tid == 0) newfront = 0;
  __syncthreads();
  if (active) {
    int e0 = bin_start[bin], e1 = bin_start[bin + 1];
    unsigned char rl = (unsigned char)r;
    for (int e = e0 + tid; e < e1; e += 256) {
      uint2 q = csr[e];
      int s = q.x >> 7;
      if (lev[s] == rl) {  // lev[d] writes below only do 255->r+1: no hazard
        atomicAdd(&slice[q.x & 127], tanhf(mcur[s]) * __uint_as_float(q.y));
        smask[q.x & 127] = 1;
      }
    }
    __syncthreads();
  }
  if (tid < BIN_SZ) {
    int d = bin * BIN_SZ + tid;
    if (d < NDST) {
      int node = ASS0 + d;
      unsigned char lv = lev[node];
      bool fired = active && (lv == (unsigned char)r) && (node < OUT0);
      mnext[node] = (fired ? 0.f : mcur[node]) + slice[tid];
      if (smask[tid] && lv == 255) {
        lev[node] = (unsigned char)(r + 1);
        if (node < OUT0) newfront = 1;  // outputs never fire -> no phantom round
      }
    }
  }
  __syncthreads();
  if (tid == 0 && newfront) flags[r + 1] = 1;
}

__global__ __launch_bounds__(256) void ko(const float* __restrict__ mem,
                                          float* __restrict__ out) {
  int i = blockIdx.x * 256 + threadIdx.x;
  if (i < OUT_F) out[i] = tanhf(mem[OUT0 + i]);
}

// ---------------------------------------------------------------------------
// Fallback dense multi-kernel path if ws too small.
// ---------------------------------------------------------------------------

__global__ __launch_bounds__(256) void k_init(float* mem, float* delta,
                                              int* status, int* got) {
  int i = blockIdx.x * 256 + threadIdx.x;
  if (i < TOTAL) {
    mem[i] = 0.f;
    delta[i] = 0.f;
    status[i] = 0;
    got[i] = 0;
  }
}
__global__ __launch_bounds__(256) void k_input(const float* __restrict__ x,
                                               const float* __restrict__ w,
                                               const int* __restrict__ src,
                                               const int* __restrict__ dst,
                                               int n, float* mem, int* got) {
  for (int e = blockIdx.x * 256 + threadIdx.x; e < n; e += gridDim.x * 256) {
    atomicAdd(&mem[dst[e]], x[src[e]] * w[e]);
    got[dst[e]] = 1;
  }
}
__global__ __launch_bounds__(256) void k_status0(int* status, int* got) {
  int i = blockIdx.x * 256 + threadIdx.x;
  if (i < TOTAL) {
    status[i] = got[i] ? 1 : 0;
    got[i] = 0;
  }
}
__global__ __launch_bounds__(256) void k_edge(const float* __restrict__ w,
                                              const int* __restrict__ src,
                                              const int* __restrict__ dst,
                                              int n,
                                              const float* __restrict__ mem,
                                              const int* __restrict__ status,
                                              float* delta, int* got) {
  for (int e = blockIdx.x * 256 + threadIdx.x; e < n; e += gridDim.x * 256) {
    int s = src[e];
    if (status[s] == 1) {
      atomicAdd(&delta[dst[e]], tanhf(mem[s]) * w[e]);
      got[dst[e]] = 1;
    }
  }
}
__global__ __launch_bounds__(256) void k_update(float* mem, float* delta,
                                                int* status, int* got) {
  int i = blockIdx.x * 256 + threadIdx.x;
  if (i < TOTAL) {
    int st = status[i];
    bool fire = (st == 1) && (i >= ASS0) && (i < OUT0);
    float d = delta[i];
    mem[i] = fire ? d : (mem[i] + d);
    status[i] = fire ? 2 : ((got[i] && st == 0) ? 1 : st);
    delta[i] = 0.f;
    got[i] = 0;
  }
}

extern "C" void kernel_launch(void* const* d_in, const int* in_sizes, int n_in,
                              void* d_out, int out_size, void* d_ws,
                              size_t ws_size, hipStream_t stream) {
  const float* x = (const float*)d_in[0];
  const float* iw = (const float*)d_in[1];
  const float* aw = (const float*)d_in[2];
  const int* ies = (const int*)d_in[3];
  const int* ied = (const int*)d_in[4];
  const int* aes = (const int*)d_in[5];
  const int* aed = (const int*)d_in[6];
  int E_in = in_sizes[1];
  int E_a = in_sizes[2];
  float* out = (float*)d_out;
  char* ws = (char*)d_ws;

  // layout: csr | mem_a | mem_b | bin_count | bin_start | bin_cursor | flags |
  //         lev
  size_t need = (size_t)E_a * 8 + (size_t)TOTAL * 8 +
                (size_t)(NBINS + (NBINS + 1) + NBINS + 32) * 4 + TOTAL;

  if (ws_size >= need) {
    uint2* csr = (uint2*)ws;
    float* mem_a = (float*)(csr + E_a);
    float* mem_b = mem_a + TOTAL;
    int* bin_count = (int*)(mem_b + TOTAL);
    int* bin_start = bin_count + NBINS;
    int* bin_cursor = bin_start + NBINS + 1;
    int* flags = bin_cursor + NBINS;
    unsigned char* lev = (unsigned char*)(flags + 32);

    kz<<<(TOTAL + 255) / 256, 256, 0, stream>>>(mem_a, (unsigned int*)lev,
                                                flags, bin_count);
    ki<<<(E_in + 255) / 256, 256, 0, stream>>>(x, iw, ies, ied, E_in, mem_a,
                                               lev);
    kh<<<NCON, 256, 0, stream>>>(aed, E_a, bin_count);
    ks<<<1, 256, 0, stream>>>(bin_count, bin_start, bin_cursor);
    kc<<<NCON, 256, 0, stream>>>(aes, aed, aw, E_a, bin_cursor, csr);

    float* bufs[2] = {mem_a, mem_b};
    for (int r = 0; r < NUM_ROUNDS; ++r)
      kR<<<NBINS, 256, 0, stream>>>(r, flags, bin_start, csr, bufs[r & 1],
                                    bufs[(r + 1) & 1], lev);
    // after 24 rounds, current buffer is bufs[24 & 1] == mem_a
    ko<<<(OUT_F + 255) / 256, 256, 0, stream>>>(mem_a, out);
    return;
  }

  // fallback: dense path
  float* mem = (float*)ws;
  float* delta = mem + TOTAL;
  int* status = (int*)(delta + TOTAL);
  int* got = status + TOTAL;
  const int nodeBlocks = (TOTAL + 255) / 256;
  k_init<<<nodeBlocks, 256, 0, stream>>>(mem, delta, status, got);
  int inBlocks = (E_in + 255) / 256;
  if (inBlocks > 1024) inBlocks = 1024;
  k_input<<<inBlocks, 256, 0, stream>>>(x, iw, ies, ied, E_in, mem, got);
  k_status0<<<nodeBlocks, 256, 0, stream>>>(status, got);
  int eBlocks = (E_a + 255) / 256;
  if (eBlocks > 2048) eBlocks = 2048;
  for (int r = 0; r < NUM_ROUNDS; ++r) {
    k_edge<<<eBlocks, 256, 0, stream>>>(aw, aes, aed, E_a, mem, status, delta,
                                        got);
    k_update<<<nodeBlocks, 256, 0, stream>>>(mem, delta, status, got);
  }
  ko<<<(OUT_F + 255) / 256, 256, 0, stream>>>(mem, out);
}

// Round 6
// 241.272 us; speedup vs baseline: 6.5472x; 1.0421x over previous
//
#include <hip/hip_runtime.h>

#define IN_F 1024
#define ASS 100000
#define OUT_F 1024
#define TOTAL (IN_F + ASS + OUT_F)  // 102048
#define ASS0 IN_F
#define OUT0 (IN_F + ASS)
#define NDST (ASS + OUT_F)  // 101024 destinations, node = ASS0 + d
#define NUM_ROUNDS 24

#define BIN_SZ 256  // dst nodes per bin (8 bits of payload)
#define NBINS ((NDST + BIN_SZ - 1) / BIN_SZ)  // 395
#define NCON 256    // construction blocks

typedef int i4v __attribute__((ext_vector_type(4)));
typedef float f4v __attribute__((ext_vector_type(4)));
typedef unsigned int u2v __attribute__((ext_vector_type(2)));

// ---------------------------------------------------------------------------
// Each assoc neuron fires exactly once at BFS level L(u).
// Single mem buffer + tv[] (tanh snapshot at fire time), snapshot fused into
// the epilogue of the round that assigns the level:
//   round r (one block per 256-dst bin, owner-exclusive writes):
//     edges with lev[src]==r: slice[dstoff] += tv[src]*w  (LDS atomics)
//     epilogue per owned d with smask: nv = mem+slice;
//       first receipt (lev==255): lev=r+1; assoc: tv=tanh(nv), mem=0 (fires
//       next round), flag frontier; output: mem=nv. Else: mem=nv.
//   Empty rounds (flags[r]==0) return immediately -- no copy, no traffic.
// ---------------------------------------------------------------------------

__global__ __launch_bounds__(256) void kz(float* mem, unsigned int* lev32,
                                          int* flags, int* bin_count) {
  int i = blockIdx.x * 256 + threadIdx.x;
  int gs = gridDim.x * 256;
  for (int k = i; k < TOTAL; k += gs) mem[k] = 0.f;
  for (int k = i; k < TOTAL / 4; k += gs) lev32[k] = 0xFFFFFFFFu;
  for (int k = i; k < NBINS; k += gs) bin_count[k] = 0;
  if (i < 32) flags[i] = 0;
}

__global__ __launch_bounds__(256) void ki(const float* __restrict__ x,
                                          const float* __restrict__ iw,
                                          const int* __restrict__ ies,
                                          const int* __restrict__ ied, int E_in,
                                          float* mem, unsigned char* lev) {
  int e = blockIdx.x * 256 + threadIdx.x;
  if (e < E_in) {
    int d = ied[e];
    atomicAdd(&mem[d], x[ies[e]] * iw[e]);
    lev[d] = 0;  // benign race: all writers store 0
  }
}

// snapshot level-0 frontier: tv = tanh(mem), mem = 0
__global__ __launch_bounds__(256) void kp(
    float* mem, float* tv, const unsigned char* __restrict__ lev) {
  int i = blockIdx.x * 256 + threadIdx.x;
  if (i < ASS) {
    int node = ASS0 + i;
    if (lev[node] == 0) {
      tv[node] = tanhf(mem[node]);
      mem[node] = 0.f;
    }
  }
}

// histogram of edges per dst-bin (vectorized, nontemporal)
__global__ __launch_bounds__(256) void kh(const int* __restrict__ aed, int E_a,
                                          int* bin_count) {
  __shared__ int h[NBINS];
  for (int b = threadIdx.x; b < NBINS; b += 256) h[b] = 0;
  __syncthreads();
  const i4v* aed4 = (const i4v*)aed;
  int nv4 = E_a >> 2;
  int stride = gridDim.x * 256;
  for (int v = blockIdx.x * 256 + (int)threadIdx.x; v < nv4; v += stride) {
    i4v d4 = __builtin_nontemporal_load(&aed4[v]);
    atomicAdd(&h[(d4.x - ASS0) >> 8], 1);
    atomicAdd(&h[(d4.y - ASS0) >> 8], 1);
    atomicAdd(&h[(d4.z - ASS0) >> 8], 1);
    atomicAdd(&h[(d4.w - ASS0) >> 8], 1);
  }
  if (blockIdx.x == 0) {
    for (int e = (nv4 << 2) + (int)threadIdx.x; e < E_a; e += 256)
      atomicAdd(&h[(aed[e] - ASS0) >> 8], 1);
  }
  __syncthreads();
  for (int b = threadIdx.x; b < NBINS; b += 256)
    if (h[b]) atomicAdd(&bin_count[b], h[b]);
}

// exclusive scan of bin counts (single block)
__global__ __launch_bounds__(256) void ks(const int* __restrict__ bin_count,
                                          int* bin_start, int* bin_cursor) {
  __shared__ int sb[1024];
  __shared__ int sp[256];
  int tid = threadIdx.x;
  for (int k = 0; k < 4; ++k) {
    int t = tid + k * 256;
    sb[t] = (t < NBINS) ? bin_count[t] : 0;
  }
  __syncthreads();
  int i0 = tid * 4;
  int s = sb[i0] + sb[i0 + 1] + sb[i0 + 2] + sb[i0 + 3];
  sp[tid] = s;
  __syncthreads();
  for (int off = 1; off < 256; off <<= 1) {
    int v = (tid >= off) ? sp[tid - off] : 0;
    __syncthreads();
    sp[tid] += v;
    __syncthreads();
  }
  int run = (tid > 0) ? sp[tid - 1] : 0;
  for (int j = 0; j < 4; ++j) {
    int t = i0 + j;
    if (t < NBINS) {
      bin_start[t] = run;
      bin_cursor[t] = run;
    }
    run += sb[t];
  }
  if (tid == 255) bin_start[NBINS] = sp[255];
}

// scatter edges into bin-grouped layout; payload = (src<<8 | dstoff, w)
__global__ __launch_bounds__(256) void kc(const int* __restrict__ aes,
                                          const int* __restrict__ aed,
                                          const float* __restrict__ aw, int E_a,
                                          int* bin_cursor,
                                          u2v* __restrict__ csr) {
  __shared__ int h[NBINS];
  for (int b = threadIdx.x; b < NBINS; b += 256) h[b] = 0;
  __syncthreads();
  const i4v* aed4 = (const i4v*)aed;
  const i4v* aes4 = (const i4v*)aes;
  const f4v* aw4 = (const f4v*)aw;
  int nv4 = E_a >> 2;
  int stride = gridDim.x * 256;
  // pass 1: local histogram
  for (int v = blockIdx.x * 256 + (int)threadIdx.x; v < nv4; v += stride) {
    i4v d4 = __builtin_nontemporal_load(&aed4[v]);
    atomicAdd(&h[(d4.x - ASS0) >> 8], 1);
    atomicAdd(&h[(d4.y - ASS0) >> 8], 1);
    atomicAdd(&h[(d4.z - ASS0) >> 8], 1);
    atomicAdd(&h[(d4.w - ASS0) >> 8], 1);
  }
  if (blockIdx.x == 0) {
    for (int e = (nv4 << 2) + (int)threadIdx.x; e < E_a; e += 256)
      atomicAdd(&h[(aed[e] - ASS0) >> 8], 1);
  }
  __syncthreads();
  // reserve contiguous global ranges per (block, bin)
  for (int b = threadIdx.x; b < NBINS; b += 256) {
    int c = h[b];
    if (c) h[b] = atomicAdd(&bin_cursor[b], c);
  }
  __syncthreads();
  // pass 2: scatter (same edge set per block as pass 1)
  for (int v = blockIdx.x * 256 + (int)threadIdx.x; v < nv4; v += stride) {
    i4v d4 = __builtin_nontemporal_load(&aed4[v]);
    i4v s4 = __builtin_nontemporal_load(&aes4[v]);
    f4v w4 = __builtin_nontemporal_load(&aw4[v]);
#pragma unroll
    for (int j = 0; j < 4; ++j) {
      int d = d4[j] - ASS0;
      int pos = atomicAdd(&h[d >> 8], 1);
      u2v q;
      q.x = ((unsigned)s4[j] << 8) | (unsigned)(d & 255);
      q.y = __float_as_uint(w4[j]);
      csr[pos] = q;
    }
  }
  if (blockIdx.x == 0) {
    for (int e = (nv4 << 2) + (int)threadIdx.x; e < E_a; e += 256) {
      int d = aed[e] - ASS0;
      int pos = atomicAdd(&h[d >> 8], 1);
      u2v q;
      q.x = ((unsigned)aes[e] << 8) | (unsigned)(d & 255);
      q.y = __float_as_uint(aw[e]);
      csr[pos] = q;
    }
  }
}

// one propagation round; grid = NBINS blocks; single mem buffer
__global__ __launch_bounds__(256) void kR(int r, int* flags,
                                          const int* __restrict__ bin_start,
                                          const u2v* __restrict__ csr,
                                          float* __restrict__ mem,
                                          float* __restrict__ tv,
                                          unsigned char* lev) {
  if (r > 0 && flags[r] == 0) return;  // uniform: empty round is a no-op
  __shared__ float slice[BIN_SZ];
  __shared__ int smask[BIN_SZ];
  __shared__ int newfront;
  int tid = threadIdx.x;
  int bin = blockIdx.x;
  slice[tid] = 0.f;
  smask[tid] = 0;
  if (tid == 0) newfront = 0;
  __syncthreads();
  int e0 = bin_start[bin], e1 = bin_start[bin + 1];
  unsigned char rl = (unsigned char)r;
  for (int e = e0 + tid; e < e1; e += 256) {
    u2v q = __builtin_nontemporal_load(&csr[e]);
    int s = (int)(q.x >> 8);
    if (lev[s] == rl) {  // concurrent lev[d] writes are 255->r+1: never ==r
      atomicAdd(&slice[q.x & 255], tv[s] * __uint_as_float(q.y));
      smask[q.x & 255] = 1;
    }
  }
  __syncthreads();
  int d = bin * BIN_SZ + tid;
  if (d < NDST && smask[tid]) {
    int node = ASS0 + d;
    float nv = mem[node] + slice[tid];
    unsigned char lv = lev[node];
    if (lv == 255) {  // first receipt: becomes working, fires next round
      lev[node] = (unsigned char)(r + 1);
      if (node < OUT0) {
        tv[node] = tanhf(nv);  // snapshot at fire time
        mem[node] = 0.f;       // "fired neurons erase memory"
        newfront = 1;          // benign LDS race: all store 1
      } else {
        mem[node] = nv;  // outputs never fire, just accumulate
      }
    } else {
      mem[node] = nv;  // already fired/working: keep accumulating
    }
  }
  __syncthreads();
  if (tid == 0 && newfront) flags[r + 1] = 1;
}

__global__ __launch_bounds__(256) void ko(const float* __restrict__ mem,
                                          float* __restrict__ out) {
  int i = blockIdx.x * 256 + threadIdx.x;
  if (i < OUT_F) out[i] = tanhf(mem[OUT0 + i]);
}

// ---------------------------------------------------------------------------
// Fallback dense multi-kernel path if ws too small.
// ---------------------------------------------------------------------------

__global__ __launch_bounds__(256) void k_init(float* mem, float* delta,
                                              int* status, int* got) {
  int i = blockIdx.x * 256 + threadIdx.x;
  if (i < TOTAL) {
    mem[i] = 0.f;
    delta[i] = 0.f;
    status[i] = 0;
    got[i] = 0;
  }
}
__global__ __launch_bounds__(256) void k_input(const float* __restrict__ x,
                                               const float* __restrict__ w,
                                               const int* __restrict__ src,
                                               const int* __restrict__ dst,
                                               int n, float* mem, int* got) {
  for (int e = blockIdx.x * 256 + threadIdx.x; e < n; e += gridDim.x * 256) {
    atomicAdd(&mem[dst[e]], x[src[e]] * w[e]);
    got[dst[e]] = 1;
  }
}
__global__ __launch_bounds__(256) void k_status0(int* status, int* got) {
  int i = blockIdx.x * 256 + threadIdx.x;
  if (i < TOTAL) {
    status[i] = got[i] ? 1 : 0;
    got[i] = 0;
  }
}
__global__ __launch_bounds__(256) void k_edge(const float* __restrict__ w,
                                              const int* __restrict__ src,
                                              const int* __restrict__ dst,
                                              int n,
                                              const float* __restrict__ mem,
                                              const int* __restrict__ status,
                                              float* delta, int* got) {
  for (int e = blockIdx.x * 256 + threadIdx.x; e < n; e += gridDim.x * 256) {
    int s = src[e];
    if (status[s] == 1) {
      atomicAdd(&delta[dst[e]], tanhf(mem[s]) * w[e]);
      got[dst[e]] = 1;
    }
  }
}
__global__ __launch_bounds__(256) void k_update(float* mem, float* delta,
                                                int* status, int* got) {
  int i = blockIdx.x * 256 + threadIdx.x;
  if (i < TOTAL) {
    int st = status[i];
    bool fire = (st == 1) && (i >= ASS0) && (i < OUT0);
    float d = delta[i];
    mem[i] = fire ? d : (mem[i] + d);
    status[i] = fire ? 2 : ((got[i] && st == 0) ? 1 : st);
    delta[i] = 0.f;
    got[i] = 0;
  }
}

extern "C" void kernel_launch(void* const* d_in, const int* in_sizes, int n_in,
                              void* d_out, int out_size, void* d_ws,
                              size_t ws_size, hipStream_t stream) {
  const float* x = (const float*)d_in[0];
  const float* iw = (const float*)d_in[1];
  const float* aw = (const float*)d_in[2];
  const int* ies = (const int*)d_in[3];
  const int* ied = (const int*)d_in[4];
  const int* aes = (const int*)d_in[5];
  const int* aed = (const int*)d_in[6];
  int E_in = in_sizes[1];
  int E_a = in_sizes[2];
  float* out = (float*)d_out;
  char* ws = (char*)d_ws;

  // layout: csr | mem | tv | bin_count | bin_start | bin_cursor | flags | lev
  size_t need = (size_t)E_a * 8 + (size_t)TOTAL * 8 +
                (size_t)(NBINS + (NBINS + 1) + NBINS + 32) * 4 + TOTAL;

  if (ws_size >= need) {
    u2v* csr = (u2v*)ws;
    float* mem = (float*)(csr + E_a);
    float* tv = mem + TOTAL;
    int* bin_count = (int*)(tv + TOTAL);
    int* bin_start = bin_count + NBINS;
    int* bin_cursor = bin_start + NBINS + 1;
    int* flags = bin_cursor + NBINS;
    unsigned char* lev = (unsigned char*)(flags + 32);

    kz<<<(TOTAL + 255) / 256, 256, 0, stream>>>(mem, (unsigned int*)lev, flags,
                                                bin_count);
    ki<<<(E_in + 255) / 256, 256, 0, stream>>>(x, iw, ies, ied, E_in, mem, lev);
    kp<<<(ASS + 255) / 256, 256, 0, stream>>>(mem, tv, lev);
    kh<<<NCON, 256, 0, stream>>>(aed, E_a, bin_count);
    ks<<<1, 256, 0, stream>>>(bin_count, bin_start, bin_cursor);
    kc<<<NCON, 256, 0, stream>>>(aes, aed, aw, E_a, bin_cursor, csr);

    for (int r = 0; r < NUM_ROUNDS; ++r)
      kR<<<NBINS, 256, 0, stream>>>(r, flags, bin_start, csr, mem, tv, lev);

    ko<<<(OUT_F + 255) / 256, 256, 0, stream>>>(mem, out);
    return;
  }

  // fallback: dense path
  float* mem = (float*)ws;
  float* delta = mem + TOTAL;
  int* status = (int*)(delta + TOTAL);
  int* got = status + TOTAL;
  const int nodeBlocks = (TOTAL + 255) / 256;
  k_init<<<nodeBlocks, 256, 0, stream>>>(mem, delta, status, got);
  int inBlocks = (E_in + 255) / 256;
  if (inBlocks > 1024) inBlocks = 1024;
  k_input<<<inBlocks, 256, 0, stream>>>(x, iw, ies, ied, E_in, mem, got);
  k_status0<<<nodeBlocks, 256, 0, stream>>>(status, got);
  int eBlocks = (E_a + 255) / 256;
  if (eBlocks > 2048) eBlocks = 2048;
  for (int r = 0; r < NUM_ROUNDS; ++r) {
    k_edge<<<eBlocks, 256, 0, stream>>>(aw, aes, aed, E_a, mem, status, delta,
                                        got);
    k_update<<<nodeBlocks, 256, 0, stream>>>(mem, delta, status, got);
  }
  ko<<<(OUT_F + 255) / 256, 256, 0, stream>>>(mem, out);
}